// Round 3
// baseline (243.746 us; speedup 1.0000x reference)
//
#include <hip/hip_runtime.h>
#include <float.h>
#include <math.h>

#define K_CODES 1024
#define ED 64
#define NTOK 131072
#define EPS 4e-4f   // flag band; approx-vs-exact bound ~7e-5 -> 6x margin

typedef __attribute__((ext_vector_type(8)))  short short8;   // 8 bf16 (4 VGPRs)
typedef __attribute__((ext_vector_type(16))) float float16;  // MFMA 32x32 acc

// ---------------------------------------------------------------------------
// NUMERICS OF THE EXACT PATH ARE FROZEN (rounds 2/4/5/6 passed, 0 flips):
//  - zsq / e_sq: numpy pairwise_sum n=64 (8 accs strided 8, mul+add no fma,
//    combine ((r0+r1)+(r2+r3))+((r4+r5)+(r6+r7))), contract(off).
//  - dot(z,e): single sequential fmaf chain over d=0..63.
//  - d2 = fmaf(-2,dot,zsq) + e_sq.
//  - argmin: first index wins (lexicographic (value,index) updates).
// Phase 1 (MFMA bf16 hi/lo) only selects candidates; tokens with a single
// in-band candidate and no in-band rival take it WITHOUT rescoring (band
// proof: all other codes are > EPS - 2*approx_err - esq_spread away).
// Exact ties inside a tile force tB==tA -> fullmask -> full 32-scan.
//
// Round-9 (this file): resubmit of round-8's restructure (round-8 bench died
// to a container/infra failure, no kernel signal; audit found no hang
// mechanism). vq_exact was latency-bound, NOT scratch-bound (round-7
// falsified that: VGPR stayed 56, dur unchanged). Root cause is structural:
// 1 thread/token = 512 blocks = 2 blocks/CU = 13% occupancy, with
// row-per-thread accesses (64 distinct cache lines per VMEM instr).
// New shape: 64 tokens/block x 2048 blocks (8 blocks/CU). Wave 0 runs the
// UNCHANGED per-lane selection (lane = token); all 4 waves then do the
// epilogue with 4 lanes/token so every z/q/store instruction is fully
// coalesced (16 contiguous lines/instr). LDS hist replaced by direct global
// atomics (same atomic count as the old flush, none of the zero/scan cost).
// SSE goes to 64 partial slots (no same-address atomic pileup); selection
// numerics and argmin order are byte-identical.
// ---------------------------------------------------------------------------

static __device__ __forceinline__ unsigned short f2bf(float x) {  // RNE
    unsigned u = __float_as_uint(x);
    u += 0x7fffu + ((u >> 16) & 1u);
    return (unsigned short)(u >> 16);
}
static __device__ __forceinline__ float bf2f(unsigned short h) {
    return __uint_as_float(((unsigned)h) << 16);
}

// ---------------------------------------------------------------------------
// pre: blocks 0..511 tokens (zsq + z bf16-split fragments);
//      blocks 512..515 codes (e_sq + e bf16-split frags, zero counts/sse).
// frag[(row32tile*8 + g)*32 + (row&31)], g = d/8, lane k-half h = g&1.
// ---------------------------------------------------------------------------
__global__ __launch_bounds__(256) void vq_pre(const float* __restrict__ z_e,
                                              const float* __restrict__ cb,
                                              float* __restrict__ zsq_g,
                                              short8* __restrict__ zfH,
                                              short8* __restrict__ zfL,
                                              float* __restrict__ e_sq,
                                              short8* __restrict__ efH,
                                              short8* __restrict__ efL,
                                              unsigned int* __restrict__ counts,
                                              float* __restrict__ sse_part)
{
#pragma clang fp contract(off)
    const int tid = threadIdx.x;
    if (blockIdx.x < NTOK / 256) {
        const int t = blockIdx.x * 256 + tid;
        const float4* zp = (const float4*)(z_e + (size_t)t * ED);
        const int n = t & 31, tt = t >> 5;
        float r[8];
#pragma unroll
        for (int g = 0; g < 8; ++g) {
            float4 a = zp[2 * g], b = zp[2 * g + 1];
            float v[8] = {a.x, a.y, a.z, a.w, b.x, b.y, b.z, b.w};
            short8 hv, lv;
#pragma unroll
            for (int j = 0; j < 8; ++j) {
                unsigned short hb = f2bf(v[j]);
                hv[j] = (short)hb;
                lv[j] = (short)f2bf(v[j] - bf2f(hb));
                const float sq = v[j] * v[j];          // frozen pairwise zsq
                r[j] = g ? (r[j] + sq) : sq;
            }
            zfH[(tt * 8 + g) * 32 + n] = hv;
            zfL[(tt * 8 + g) * 32 + n] = lv;
        }
        zsq_g[t] = ((r[0] + r[1]) + (r[2] + r[3])) + ((r[4] + r[5]) + (r[6] + r[7]));
    } else {
        const int k = (blockIdx.x - NTOK / 256) * 256 + tid;   // 0..1023
        const float4* ep = (const float4*)(cb + (size_t)k * ED);
        const int m = k & 31, ct = k >> 5;
        float r[8];
#pragma unroll
        for (int g = 0; g < 8; ++g) {
            float4 a = ep[2 * g], b = ep[2 * g + 1];
            float v[8] = {a.x, a.y, a.z, a.w, b.x, b.y, b.z, b.w};
            short8 hv, lv;
#pragma unroll
            for (int j = 0; j < 8; ++j) {
                unsigned short hb = f2bf(v[j]);
                hv[j] = (short)hb;
                lv[j] = (short)f2bf(v[j] - bf2f(hb));
                const float sq = v[j] * v[j];          // frozen pairwise e_sq
                r[j] = g ? (r[j] + sq) : sq;
            }
            efH[(ct * 8 + g) * 32 + m] = hv;
            efL[(ct * 8 + g) * 32 + m] = lv;
        }
        e_sq[k] = ((r[0] + r[1]) + (r[2] + r[3])) + ((r[4] + r[5]) + (r[6] + r[7]));
        counts[k] = 0u;
        if (k < 64) sse_part[k] = 0.f;
    }
}

// ---------------------------------------------------------------------------
// phase 1: approx scores via bf16 MFMA (hh, h*l, l*h).
// Wave owns 64 codes (2 m-tiles, A-frags in regs); blockIdx.y = code group.
// Store per (token, 32-code tile): tA = -2*maxdot (low 5 mantissa bits =
// in-tile argmax row), tB = -2*secondmax.
// ---------------------------------------------------------------------------
__global__ __launch_bounds__(256, 2) void vq_approx(const short8* __restrict__ zfH,
                                                    const short8* __restrict__ zfL,
                                                    const short8* __restrict__ efH,
                                                    const short8* __restrict__ efL,
                                                    float* __restrict__ tA,
                                                    float* __restrict__ tB)
{
    const int tid = threadIdx.x;
    const int lane = tid & 63, wv = tid >> 6;
    const int h = lane >> 5, ml = lane & 31;
    const int ct0 = blockIdx.y * 8 + wv * 2;       // wave's two 32-code tiles

    short8 ea[2][4], eb[2][4];                     // A-frags: eh, el (in regs)
#pragma unroll
    for (int mt = 0; mt < 2; ++mt) {
        const int ct = ct0 + mt;
#pragma unroll
        for (int q = 0; q < 4; ++q) {
            const int idx = (ct * 8 + q * 2 + h) * 32 + ml;
            ea[mt][q] = efH[idx];
            eb[mt][q] = efL[idx];
        }
    }

    const int tt0 = blockIdx.x * 8;
    for (int it = 0; it < 8; ++it) {
        const int tt = tt0 + it;
        short8 zh[4], zl[4];
#pragma unroll
        for (int q = 0; q < 4; ++q) {
            const int idx = (tt * 8 + q * 2 + h) * 32 + ml;
            zh[q] = zfH[idx];
            zl[q] = zfL[idx];
        }
        float16 acc0 = {}, acc1 = {};
#pragma unroll
        for (int q = 0; q < 4; ++q) {
            acc0 = __builtin_amdgcn_mfma_f32_32x32x16_bf16(ea[0][q], zh[q], acc0, 0, 0, 0);
            acc1 = __builtin_amdgcn_mfma_f32_32x32x16_bf16(ea[1][q], zh[q], acc1, 0, 0, 0);
            acc0 = __builtin_amdgcn_mfma_f32_32x32x16_bf16(ea[0][q], zl[q], acc0, 0, 0, 0);
            acc1 = __builtin_amdgcn_mfma_f32_32x32x16_bf16(ea[1][q], zl[q], acc1, 0, 0, 0);
            acc0 = __builtin_amdgcn_mfma_f32_32x32x16_bf16(eb[0][q], zh[q], acc0, 0, 0, 0);
            acc1 = __builtin_amdgcn_mfma_f32_32x32x16_bf16(eb[1][q], zh[q], acc1, 0, 0, 0);
        }
#pragma unroll
        for (int mt = 0; mt < 2; ++mt) {
            const float16 acc = mt ? acc1 : acc0;
            float v1 = -FLT_MAX, v2 = -FLT_MAX;
            int i1 = 0;
#pragma unroll
            for (int rg = 0; rg < 16; ++rg) {
                const float v = acc[rg];
                const int mrow = (rg & 3) + 8 * (rg >> 2) + 4 * h;  // C/D row (m74/m101)
                if (v > v1) { v2 = v1; v1 = v; i1 = mrow; }
                else v2 = fmaxf(v2, v);
            }
            const float o1 = __shfl_xor(v1, 32);
            const float o2 = __shfl_xor(v2, 32);
            const int   oi = __shfl_xor(i1, 32);
            const float lo = fminf(v1, o1);
            if (o1 > v1) { v1 = o1; i1 = oi; }
            v2 = fmaxf(lo, fmaxf(v2, o2));          // exact 2nd-largest merge
            if (lane < 32) {
                const int t = tt * 32 + lane;        // C/D col = token
                const unsigned bits = (__float_as_uint(-2.f * v1) & ~31u) | (unsigned)i1;
                tA[(size_t)(ct0 + mt) * NTOK + t] = __uint_as_float(bits);
                tB[(size_t)(ct0 + mt) * NTOK + t] = -2.f * v2;
            }
        }
    }
}

// ---------------------------------------------------------------------------
// phase 2: 64 tokens/block, 2048 blocks (8 blocks/CU). Wave 0: per-lane
// selection (lane = local token), numerics identical to previous rounds.
// All waves: coalesced epilogue, 4 lanes/token (lane sub owns float4s
// j*4+sub -> 16 contiguous 64B lines per VMEM instruction).
// ---------------------------------------------------------------------------

// Frozen exact rescore of code (cc): single sequential fmaf chain d=0..63,
// d2 = fmaf(-2,dot,zsq) + e_sq; lexicographic (d2, idx) update.
#define RESCORE(cc)                                                          \
    do {                                                                     \
        const int c_ = (cc);                                                 \
        const float4* e4_ = (const float4*)(cb + (size_t)c_ * ED);           \
        float a_ = 0.f;                                                      \
        _Pragma("unroll")                                                    \
        for (int jj_ = 0; jj_ < 16; ++jj_) {                                 \
            const float4 v_ = e4_[jj_];                                      \
            a_ = fmaf(zr[4 * jj_ + 0], v_.x, a_);                            \
            a_ = fmaf(zr[4 * jj_ + 1], v_.y, a_);                            \
            a_ = fmaf(zr[4 * jj_ + 2], v_.z, a_);                            \
            a_ = fmaf(zr[4 * jj_ + 3], v_.w, a_);                            \
        }                                                                    \
        const float d2_ = fmaf(-2.f, a_, zsq) + e_sq[c_];                    \
        if (d2_ < best || (d2_ == best && c_ < bi)) { best = d2_; bi = c_; } \
    } while (0)

__global__ __launch_bounds__(256, 4) void vq_exact(const float* __restrict__ z_e,
                                                   const float* __restrict__ cb,
                                                   const float* __restrict__ e_sq,
                                                   const float* __restrict__ zsq_g,
                                                   const float* __restrict__ tA,
                                                   const float* __restrict__ tB,
                                                   float* __restrict__ out_zq,
                                                   float* __restrict__ out_idx,
                                                   unsigned int* __restrict__ counts,
                                                   float* __restrict__ sse_part)
{
#pragma clang fp contract(off)
    __shared__ int   sbi[64];
    __shared__ float wsse[4];
    const int tid = threadIdx.x;
    const int wv = tid >> 6, lane = tid & 63;
    const int t0 = blockIdx.x * 64;
    const int tl = tid >> 2, sub = tid & 3;        // epilogue: token-local, quad

    // All waves: load this thread's epilogue z fragment early (fully
    // coalesced: per j-instr the 64 lanes cover 16 contiguous 64B lines).
    // Read-only data; overlaps wave 0's selection latency.
    float zf[16];
    {
        const float4* z4 = (const float4*)z_e;
#pragma unroll
        for (int j = 0; j < 4; ++j) {
            const float4 v = z4[(size_t)(t0 + tl) * 16 + j * 4 + sub];
            zf[4 * j + 0] = v.x; zf[4 * j + 1] = v.y;
            zf[4 * j + 2] = v.z; zf[4 * j + 3] = v.w;
        }
    }

    if (wv == 0) {
        // ---------------- selection: lane = local token (UNCHANGED) -------
        const int t = t0 + lane;
        float av[32];
        float m = FLT_MAX;
#pragma unroll
        for (int ct = 0; ct < 32; ++ct) {
            av[ct] = tA[(size_t)ct * NTOK + t];
            m = fminf(m, av[ct]);
        }
        const float thr = m + EPS;

        unsigned bandmask = 0u, fullmask = 0u;
        int cand0 = 0, nband = 0;
#pragma unroll
        for (int ct = 0; ct < 32; ++ct) {
            if (av[ct] <= thr) {
                if (nband == 0)
                    cand0 = ct * 32 + (int)(__float_as_uint(av[ct]) & 31u);
                ++nband;
                bandmask |= (1u << ct);
                if (tB[(size_t)ct * NTOK + t] <= thr) fullmask |= (1u << ct);
            }
        }

        int bsel;
        if (nband == 1 && fullmask == 0u) {
            bsel = cand0;               // unambiguous: band proves exact argmin
        } else {
            // Rare path: load z (same order as always), frozen rescore.
            const float4* zp = (const float4*)(z_e + (size_t)t * ED);
            float zr[ED];
#pragma unroll
            for (int i = 0; i < 16; ++i) {
                const float4 v = zp[i];
                zr[4 * i + 0] = v.x; zr[4 * i + 1] = v.y;
                zr[4 * i + 2] = v.z; zr[4 * i + 3] = v.w;
            }
            const float zsq = zsq_g[t];
            float best = FLT_MAX;
            int bi = 0;
            unsigned rem = bandmask;
            while (rem) {
                const int ct = __ffs(rem) - 1;
                rem &= rem - 1;
                if (fullmask & (1u << ct)) {
                    for (int j = 0; j < 32; ++j) RESCORE(ct * 32 + j);
                } else {
                    const int c = ct * 32 +
                        (int)(__float_as_uint(tA[(size_t)ct * NTOK + t]) & 31u);
                    RESCORE(c);
                }
            }
            bsel = bi;
        }

        sbi[lane] = bsel;
        out_idx[t] = (float)bsel;                  // coalesced 256B
        atomicAdd(&counts[bsel], 1u);              // direct global histogram
    }
    __syncthreads();

    // ---------------- epilogue: 4 lanes/token, fully coalesced ------------
    const int bi = sbi[tl];
    const float4* eq4 = (const float4*)cb;
    float4* oz4 = (float4*)out_zq;
    float lsse = 0.f;
#pragma unroll
    for (int j = 0; j < 4; ++j) {
        const float4 q = eq4[(size_t)bi * 16 + j * 4 + sub];   // quad-coalesced
        oz4[(size_t)(t0 + tl) * 16 + j * 4 + sub] = q;         // coalesced
        float dx = q.x - zf[4 * j + 0]; lsse = fmaf(dx, dx, lsse);
        float dy = q.y - zf[4 * j + 1]; lsse = fmaf(dy, dy, lsse);
        float dz = q.z - zf[4 * j + 2]; lsse = fmaf(dz, dz, lsse);
        float dw = q.w - zf[4 * j + 3]; lsse = fmaf(dw, dw, lsse);
    }
#pragma unroll
    for (int off = 32; off > 0; off >>= 1)
        lsse += __shfl_down(lsse, off, 64);
    if (lane == 0) wsse[wv] = lsse;
    __syncthreads();
    if (tid == 0)
        atomicAdd(&sse_part[blockIdx.x & 63],
                  (wsse[0] + wsse[1]) + (wsse[2] + wsse[3]));
}

// ---------------------------------------------------------------------------
// final: entropy / losses scalars (sums 64 SSE partials)
// ---------------------------------------------------------------------------
__global__ __launch_bounds__(1024) void vq_final(const unsigned int* __restrict__ counts,
                                                 const float* __restrict__ sse_part,
                                                 float* __restrict__ out_sc)
{
    __shared__ float red[1024];
    const int i = threadIdx.x;
    const float c = (float)counts[i];
    const float p = c / (float)NTOK + 1e-10f;
    red[i] = p * logf(p);
    __syncthreads();
    for (int s = 512; s > 0; s >>= 1) {
        if (i < s) red[i] += red[i + s];
        __syncthreads();
    }
    if (i == 0) {
        const float entropy = -red[0];
        float ssum = 0.f;
        for (int k = 0; k < 64; ++k) ssum += sse_part[k];
        const float cbl = ssum / ((float)NTOK * (float)ED);
        out_sc[0] = cbl;                                   // codebook_loss
        out_sc[1] = 0.25f * cbl;                           // commitment_loss
        out_sc[2] = -0.1f * (entropy / 6.93147180559945f); // entropy_loss
        out_sc[3] = expf(entropy);                         // perplexity
    }
}

// ---------------------------------------------------------------------------
extern "C" void kernel_launch(void* const* d_in, const int* in_sizes, int n_in,
                              void* d_out, int out_size, void* d_ws, size_t ws_size,
                              hipStream_t stream)
{
    const float* z_e = (const float*)d_in[0];
    const float* cb  = (const float*)d_in[1];

    float* out   = (float*)d_out;
    float* o_zq  = out;                              // [131072,64]
    float* o_idx = out + (size_t)NTOK * ED;          // [131072] (as float)
    float* o_sc  = o_idx + NTOK;                     // 4 scalars

    char* ws = (char*)d_ws;
    float*        e_sq     = (float*)(ws);                   // 4 KB
    unsigned int* counts   = (unsigned int*)(ws + 4096);     // 4 KB
    float*        sse_part = (float*)(ws + 8192);            // 256 B (64 fl)
    float*        zsq_g    = (float*)(ws + 8448);            // 512 KB
    short8*       efH      = (short8*)(ws + 532736);         // 128 KB
    short8*       efL      = (short8*)(ws + 663808);         // 128 KB
    short8*       zfH      = (short8*)(ws + (1u << 20));     // 16 MB
    short8*       zfL      = (short8*)(ws + 17825792);       // 16 MB
    float*        tA       = (float*)(ws + 34603008);        // 16 MB
    float*        tB       = (float*)(ws + 51380224);        // 16 MB (end 64 MB)

    vq_pre   <<<NTOK / 256 + 4, 256, 0, stream>>>(z_e, cb, zsq_g, zfH, zfL,
                                                  e_sq, efH, efL, counts, sse_part);
    vq_approx<<<dim3(NTOK / 256, 4), 256, 0, stream>>>(zfH, zfL, efH, efL, tA, tB);
    vq_exact <<<NTOK / 64, 256, 0, stream>>>(z_e, cb, e_sq, zsq_g, tA, tB,
                                             o_zq, o_idx, counts, sse_part);
    vq_final <<<1, 1024, 0, stream>>>(counts, sse_part, o_sc);
}

// Round 4
// 215.706 us; speedup vs baseline: 1.1300x; 1.1300x over previous
//
#include <hip/hip_runtime.h>
#include <float.h>
#include <math.h>

#define K_CODES 1024
#define ED 64
#define NTOK 131072
#define EPS 4e-4f   // flag band; approx-vs-exact bound ~7e-5 -> 6x margin

typedef __attribute__((ext_vector_type(8)))  short short8;   // 8 bf16 (4 VGPRs)
typedef __attribute__((ext_vector_type(16))) float float16;  // MFMA 32x32 acc

// ---------------------------------------------------------------------------
// NUMERICS OF THE EXACT PATH ARE FROZEN (rounds 2/4/5/6 passed, 0 flips):
//  - zsq / e_sq: numpy pairwise_sum n=64 (8 accs strided 8, mul+add no fma,
//    combine ((r0+r1)+(r2+r3))+((r4+r5)+(r6+r7))), contract(off).
//  - dot(z,e): single sequential fmaf chain over d=0..63.
//  - d2 = fmaf(-2,dot,zsq) + e_sq.
//  - argmin: first index wins (lexicographic (value,index) updates).
// Phase 1 (MFMA bf16 hi/lo) only selects candidates; tokens with a single
// in-band candidate and no in-band rival take it WITHOUT rescoring.
// Exact ties inside a tile force tB==tA -> fullmask -> full 32-scan.
//
// Round-10 (this file): selection parallelism was the wall. 1 thread/token
// caps selection at 2048 waves = 8/CU = 25% occupancy; round-3's wave0-only
// selection made it 4x WORSE (2 selection-waves/CU, 96us). New vq_exact:
// 2 lanes/token (halves h=lane>>5 own 16 tiles each, merged via
// __shfl_xor(..,32)) -> 4096 waves = 16/CU = 50% occupancy, every lane
// active in every phase, per-lane dependent chain halved. tA/tB fused into
// one float2 (tAB) so the rival value rides the same 8-B load as the max --
// the dependent tB round-trip is gone from the common path. Lex (d2,idx)
// fold per half + lex pair-merge == the frozen sequential 0..31 fold (same
// candidate set, identical per-candidate RESCORE chain). Epilogue is
// flat-contiguous (thread<->float4). Counts atomics sharded x4 by block.
// ---------------------------------------------------------------------------

static __device__ __forceinline__ unsigned short f2bf(float x) {  // RNE
    unsigned u = __float_as_uint(x);
    u += 0x7fffu + ((u >> 16) & 1u);
    return (unsigned short)(u >> 16);
}
static __device__ __forceinline__ float bf2f(unsigned short h) {
    return __uint_as_float(((unsigned)h) << 16);
}

// ---------------------------------------------------------------------------
// pre: blocks 0..511 tokens (zsq + z bf16-split fragments);
//      blocks 512..515 codes (e_sq + e bf16-split frags, zero counts/sse).
// frag[(row32tile*8 + g)*32 + (row&31)], g = d/8, lane k-half h = g&1.
// ---------------------------------------------------------------------------
__global__ __launch_bounds__(256) void vq_pre(const float* __restrict__ z_e,
                                              const float* __restrict__ cb,
                                              float* __restrict__ zsq_g,
                                              short8* __restrict__ zfH,
                                              short8* __restrict__ zfL,
                                              float* __restrict__ e_sq,
                                              short8* __restrict__ efH,
                                              short8* __restrict__ efL,
                                              unsigned int* __restrict__ counts,
                                              float* __restrict__ sse_part)
{
#pragma clang fp contract(off)
    const int tid = threadIdx.x;
    if (blockIdx.x < NTOK / 256) {
        const int t = blockIdx.x * 256 + tid;
        const float4* zp = (const float4*)(z_e + (size_t)t * ED);
        const int n = t & 31, tt = t >> 5;
        float r[8];
#pragma unroll
        for (int g = 0; g < 8; ++g) {
            float4 a = zp[2 * g], b = zp[2 * g + 1];
            float v[8] = {a.x, a.y, a.z, a.w, b.x, b.y, b.z, b.w};
            short8 hv, lv;
#pragma unroll
            for (int j = 0; j < 8; ++j) {
                unsigned short hb = f2bf(v[j]);
                hv[j] = (short)hb;
                lv[j] = (short)f2bf(v[j] - bf2f(hb));
                const float sq = v[j] * v[j];          // frozen pairwise zsq
                r[j] = g ? (r[j] + sq) : sq;
            }
            zfH[(tt * 8 + g) * 32 + n] = hv;
            zfL[(tt * 8 + g) * 32 + n] = lv;
        }
        zsq_g[t] = ((r[0] + r[1]) + (r[2] + r[3])) + ((r[4] + r[5]) + (r[6] + r[7]));
    } else {
        const int k = (blockIdx.x - NTOK / 256) * 256 + tid;   // 0..1023
        const float4* ep = (const float4*)(cb + (size_t)k * ED);
        const int m = k & 31, ct = k >> 5;
        float r[8];
#pragma unroll
        for (int g = 0; g < 8; ++g) {
            float4 a = ep[2 * g], b = ep[2 * g + 1];
            float v[8] = {a.x, a.y, a.z, a.w, b.x, b.y, b.z, b.w};
            short8 hv, lv;
#pragma unroll
            for (int j = 0; j < 8; ++j) {
                unsigned short hb = f2bf(v[j]);
                hv[j] = (short)hb;
                lv[j] = (short)f2bf(v[j] - bf2f(hb));
                const float sq = v[j] * v[j];          // frozen pairwise e_sq
                r[j] = g ? (r[j] + sq) : sq;
            }
            efH[(ct * 8 + g) * 32 + m] = hv;
            efL[(ct * 8 + g) * 32 + m] = lv;
        }
        e_sq[k] = ((r[0] + r[1]) + (r[2] + r[3])) + ((r[4] + r[5]) + (r[6] + r[7]));
        counts[k]            = 0u;   // 4 shards
        counts[k + 1024]     = 0u;
        counts[k + 2048]     = 0u;
        counts[k + 3072]     = 0u;
        if (k < 64) sse_part[k] = 0.f;
    }
}

// ---------------------------------------------------------------------------
// phase 1: approx scores via bf16 MFMA (hh, h*l, l*h).
// Wave owns 64 codes (2 m-tiles, A-frags in regs); blockIdx.y = code group.
// Store per (token, 32-code tile): tAB.x = -2*maxdot (low 5 mantissa bits =
// in-tile argmax row), tAB.y = -2*secondmax. One coalesced float2 store.
// ---------------------------------------------------------------------------
__global__ __launch_bounds__(256, 2) void vq_approx(const short8* __restrict__ zfH,
                                                    const short8* __restrict__ zfL,
                                                    const short8* __restrict__ efH,
                                                    const short8* __restrict__ efL,
                                                    float2* __restrict__ tAB)
{
    const int tid = threadIdx.x;
    const int lane = tid & 63, wv = tid >> 6;
    const int h = lane >> 5, ml = lane & 31;
    const int ct0 = blockIdx.y * 8 + wv * 2;       // wave's two 32-code tiles

    short8 ea[2][4], eb[2][4];                     // A-frags: eh, el (in regs)
#pragma unroll
    for (int mt = 0; mt < 2; ++mt) {
        const int ct = ct0 + mt;
#pragma unroll
        for (int q = 0; q < 4; ++q) {
            const int idx = (ct * 8 + q * 2 + h) * 32 + ml;
            ea[mt][q] = efH[idx];
            eb[mt][q] = efL[idx];
        }
    }

    const int tt0 = blockIdx.x * 8;
    for (int it = 0; it < 8; ++it) {
        const int tt = tt0 + it;
        short8 zh[4], zl[4];
#pragma unroll
        for (int q = 0; q < 4; ++q) {
            const int idx = (tt * 8 + q * 2 + h) * 32 + ml;
            zh[q] = zfH[idx];
            zl[q] = zfL[idx];
        }
        float16 acc0 = {}, acc1 = {};
#pragma unroll
        for (int q = 0; q < 4; ++q) {
            acc0 = __builtin_amdgcn_mfma_f32_32x32x16_bf16(ea[0][q], zh[q], acc0, 0, 0, 0);
            acc1 = __builtin_amdgcn_mfma_f32_32x32x16_bf16(ea[1][q], zh[q], acc1, 0, 0, 0);
            acc0 = __builtin_amdgcn_mfma_f32_32x32x16_bf16(ea[0][q], zl[q], acc0, 0, 0, 0);
            acc1 = __builtin_amdgcn_mfma_f32_32x32x16_bf16(ea[1][q], zl[q], acc1, 0, 0, 0);
            acc0 = __builtin_amdgcn_mfma_f32_32x32x16_bf16(eb[0][q], zh[q], acc0, 0, 0, 0);
            acc1 = __builtin_amdgcn_mfma_f32_32x32x16_bf16(eb[1][q], zh[q], acc1, 0, 0, 0);
        }
#pragma unroll
        for (int mt = 0; mt < 2; ++mt) {
            const float16 acc = mt ? acc1 : acc0;
            float v1 = -FLT_MAX, v2 = -FLT_MAX;
            int i1 = 0;
#pragma unroll
            for (int rg = 0; rg < 16; ++rg) {
                const float v = acc[rg];
                const int mrow = (rg & 3) + 8 * (rg >> 2) + 4 * h;  // C/D row (m74/m101)
                if (v > v1) { v2 = v1; v1 = v; i1 = mrow; }
                else v2 = fmaxf(v2, v);
            }
            const float o1 = __shfl_xor(v1, 32);
            const float o2 = __shfl_xor(v2, 32);
            const int   oi = __shfl_xor(i1, 32);
            const float lo = fminf(v1, o1);
            if (o1 > v1) { v1 = o1; i1 = oi; }
            v2 = fmaxf(lo, fmaxf(v2, o2));          // exact 2nd-largest merge
            if (lane < 32) {
                const int t = tt * 32 + lane;        // C/D col = token
                const unsigned bits = (__float_as_uint(-2.f * v1) & ~31u) | (unsigned)i1;
                float2 o;
                o.x = __uint_as_float(bits);
                o.y = -2.f * v2;
                tAB[(size_t)(ct0 + mt) * NTOK + t] = o;   // 256B coalesced
            }
        }
    }
}

// ---------------------------------------------------------------------------
// phase 2: 128 tokens/block, 1024 blocks, 2 lanes/token selection.
// Half h owns tiles h*16..h*16+15; pair merge via __shfl_xor(..,32).
// ---------------------------------------------------------------------------

// Frozen exact rescore of code (cc): single sequential fmaf chain d=0..63,
// d2 = fmaf(-2,dot,zsq) + e_sq; lexicographic (d2, idx) update.
#define RESCORE(cc)                                                          \
    do {                                                                     \
        const int c_ = (cc);                                                 \
        const float4* e4_ = (const float4*)(cb + (size_t)c_ * ED);           \
        float a_ = 0.f;                                                      \
        _Pragma("unroll")                                                    \
        for (int jj_ = 0; jj_ < 16; ++jj_) {                                 \
            const float4 v_ = e4_[jj_];                                      \
            a_ = fmaf(zr[4 * jj_ + 0], v_.x, a_);                            \
            a_ = fmaf(zr[4 * jj_ + 1], v_.y, a_);                            \
            a_ = fmaf(zr[4 * jj_ + 2], v_.z, a_);                            \
            a_ = fmaf(zr[4 * jj_ + 3], v_.w, a_);                            \
        }                                                                    \
        const float d2_ = fmaf(-2.f, a_, zsq) + e_sq[c_];                    \
        if (d2_ < best || (d2_ == best && c_ < bi)) { best = d2_; bi = c_; } \
    } while (0)

__global__ __launch_bounds__(256, 4) void vq_exact(const float* __restrict__ z_e,
                                                   const float* __restrict__ cb,
                                                   const float* __restrict__ e_sq,
                                                   const float* __restrict__ zsq_g,
                                                   const float2* __restrict__ tAB,
                                                   float* __restrict__ out_zq,
                                                   float* __restrict__ out_idx,
                                                   unsigned int* __restrict__ counts,
                                                   float* __restrict__ sse_part)
{
#pragma clang fp contract(off)
    __shared__ int   sbi[128];
    __shared__ float wsse[4];
    const int tid = threadIdx.x;
    const int wv = tid >> 6, lane = tid & 63;
    const int h = lane >> 5;                       // tile half (16 tiles each)
    const int tl = wv * 32 + (lane & 31);          // block-local token 0..127
    const int t0 = blockIdx.x * 128;
    const int t = t0 + tl;

    // ---- selection scan: half h loads its 16 (max,rival) pairs -----------
    float av[16], bv[16];
    float m = FLT_MAX;
#pragma unroll
    for (int i = 0; i < 16; ++i) {
        const float2 p = tAB[(size_t)(h * 16 + i) * NTOK + t];
        av[i] = p.x; bv[i] = p.y;
        m = fminf(m, av[i]);
    }
    m = fminf(m, __shfl_xor(m, 32));               // pair min == frozen min32
    const float thr = m + EPS;

    unsigned band16 = 0u, full16 = 0u;
    int cand0 = 0, nb = 0;
#pragma unroll
    for (int i = 0; i < 16; ++i) {
        if (av[i] <= thr) {
            if (nb == 0)
                cand0 = (h * 16 + i) * 32 + (int)(__float_as_uint(av[i]) & 31u);
            ++nb;
            band16 |= (1u << i);
            if (bv[i] <= thr) full16 |= (1u << i);
        }
    }
    const int nb_o   = __shfl_xor(nb, 32);
    const int c0_o   = __shfl_xor(cand0, 32);
    const unsigned full_o = (unsigned)__shfl_xor((int)full16, 32);

    int bsel;
    if ((nb + nb_o) == 1 && (full16 | full_o) == 0u) {
        // unambiguous: band proves exact argmin; take whichever half has it
        bsel = h == 0 ? (nb ? cand0 : c0_o) : (nb_o ? c0_o : cand0);
    } else {
        // Rare path: both halves rescore their own in-band tiles with the
        // frozen chain, then lex-merge (== sequential 0..31 fold).
        const float4* zp = (const float4*)(z_e + (size_t)t * ED);
        float zr[ED];
#pragma unroll
        for (int i = 0; i < 16; ++i) {
            const float4 v = zp[i];
            zr[4 * i + 0] = v.x; zr[4 * i + 1] = v.y;
            zr[4 * i + 2] = v.z; zr[4 * i + 3] = v.w;
        }
        const float zsq = zsq_g[t];
        float best = FLT_MAX;
        int bi = 0;
        unsigned rem = band16;
        while (rem) {
            const int i = __ffs(rem) - 1;
            rem &= rem - 1;
            const int ct = h * 16 + i;
            if (full16 & (1u << i)) {
                for (int j = 0; j < 32; ++j) RESCORE(ct * 32 + j);
            } else {
                RESCORE(ct * 32 + (int)(__float_as_uint(av[i]) & 31u));
            }
        }
        const float ob  = __shfl_xor(best, 32);
        const int   obi = __shfl_xor(bi, 32);
        if (ob < best || (ob == best && obi < bi)) { best = ob; bi = obi; }
        bsel = bi;
    }

    if (h == 0) {
        sbi[tl] = bsel;
        out_idx[t] = (float)bsel;
        atomicAdd(&counts[(blockIdx.x & 3) * K_CODES + bsel], 1u);  // sharded
    }
    __syncthreads();

    // ---- epilogue: flat-contiguous, thread <-> float4 --------------------
    const float4* z4  = (const float4*)z_e + (size_t)t0 * 16;
    float4*       o4  = (float4*)out_zq + (size_t)t0 * 16;
    const float4* eq4 = (const float4*)cb;
    float lsse = 0.f;
#pragma unroll
    for (int p = 0; p < 8; ++p) {
        const int f = p * 256 + tid;               // 0..2047 float4s
        const int bq = sbi[f >> 4];
        const float4 q  = eq4[(size_t)bq * 16 + (f & 15)];
        const float4 zv = z4[f];
        o4[f] = q;
        float dx = q.x - zv.x; lsse = fmaf(dx, dx, lsse);
        float dy = q.y - zv.y; lsse = fmaf(dy, dy, lsse);
        float dz = q.z - zv.z; lsse = fmaf(dz, dz, lsse);
        float dw = q.w - zv.w; lsse = fmaf(dw, dw, lsse);
    }
#pragma unroll
    for (int off = 32; off > 0; off >>= 1)
        lsse += __shfl_down(lsse, off, 64);
    if (lane == 0) wsse[wv] = lsse;
    __syncthreads();
    if (tid == 0)
        atomicAdd(&sse_part[blockIdx.x & 63],
                  (wsse[0] + wsse[1]) + (wsse[2] + wsse[3]));
}

// ---------------------------------------------------------------------------
// final: entropy / losses scalars (sums 4 count shards + 64 SSE partials)
// ---------------------------------------------------------------------------
__global__ __launch_bounds__(1024) void vq_final(const unsigned int* __restrict__ counts,
                                                 const float* __restrict__ sse_part,
                                                 float* __restrict__ out_sc)
{
    __shared__ float red[1024];
    const int i = threadIdx.x;
    const unsigned int cu = counts[i] + counts[i + 1024]
                          + counts[i + 2048] + counts[i + 3072];
    const float c = (float)cu;
    const float p = c / (float)NTOK + 1e-10f;
    red[i] = p * logf(p);
    __syncthreads();
    for (int s = 512; s > 0; s >>= 1) {
        if (i < s) red[i] += red[i + s];
        __syncthreads();
    }
    if (i == 0) {
        const float entropy = -red[0];
        float ssum = 0.f;
        for (int k = 0; k < 64; ++k) ssum += sse_part[k];
        const float cbl = ssum / ((float)NTOK * (float)ED);
        out_sc[0] = cbl;                                   // codebook_loss
        out_sc[1] = 0.25f * cbl;                           // commitment_loss
        out_sc[2] = -0.1f * (entropy / 6.93147180559945f); // entropy_loss
        out_sc[3] = expf(entropy);                         // perplexity
    }
}

// ---------------------------------------------------------------------------
extern "C" void kernel_launch(void* const* d_in, const int* in_sizes, int n_in,
                              void* d_out, int out_size, void* d_ws, size_t ws_size,
                              hipStream_t stream)
{
    const float* z_e = (const float*)d_in[0];
    const float* cb  = (const float*)d_in[1];

    float* out   = (float*)d_out;
    float* o_zq  = out;                              // [131072,64]
    float* o_idx = out + (size_t)NTOK * ED;          // [131072] (as float)
    float* o_sc  = o_idx + NTOK;                     // 4 scalars

    char* ws = (char*)d_ws;
    float*        e_sq     = (float*)(ws);                   // 4 KB
    unsigned int* counts   = (unsigned int*)(ws + 4096);     // 16 KB (4 shards)
    float*        sse_part = (float*)(ws + 20480);           // 256 B (64 fl)
    float*        zsq_g    = (float*)(ws + 20736);           // 512 KB -> 545024
    short8*       efH      = (short8*)(ws + 545024);         // 128 KB -> 676096
    short8*       efL      = (short8*)(ws + 676096);         // 128 KB -> 807168
    short8*       zfH      = (short8*)(ws + (1u << 20));     // 16 MB -> 17825792
    short8*       zfL      = (short8*)(ws + 17825792);       // 16 MB -> 34603008
    float2*       tAB      = (float2*)(ws + 34603008);       // 32 MB (same end)

    vq_pre   <<<NTOK / 256 + 4, 256, 0, stream>>>(z_e, cb, zsq_g, zfH, zfL,
                                                  e_sq, efH, efL, counts, sse_part);
    vq_approx<<<dim3(NTOK / 256, 4), 256, 0, stream>>>(zfH, zfL, efH, efL, tAB);
    vq_exact <<<NTOK / 128, 256, 0, stream>>>(z_e, cb, e_sq, zsq_g, tAB,
                                              o_zq, o_idx, counts, sse_part);
    vq_final <<<1, 1024, 0, stream>>>(counts, sse_part, o_sc);
}

// Round 5
// 205.116 us; speedup vs baseline: 1.1883x; 1.0516x over previous
//
#include <hip/hip_runtime.h>
#include <float.h>
#include <math.h>

#define K_CODES 1024
#define ED 64
#define NTOK 131072
#define EPS 4e-4f   // flag band; approx-vs-exact bound ~7e-5 -> 6x margin

typedef __attribute__((ext_vector_type(8)))  short short8;   // 8 bf16 (4 VGPRs)
typedef __attribute__((ext_vector_type(16))) float float16;  // MFMA 32x32 acc

// ---------------------------------------------------------------------------
// NUMERICS OF THE EXACT PATH ARE FROZEN (0 flips across all passing rounds):
//  - zsq / e_sq: numpy pairwise_sum n=64 (8 accs strided 8, mul+add no fma,
//    combine ((r0+r1)+(r2+r3))+((r4+r5)+(r6+r7))), contract(off).
//  - dot(z,e): single sequential fmaf chain over d=0..63.
//  - d2 = fmaf(-2,dot,zsq) + e_sq.
//  - argmin: first index wins (lexicographic (value,index) updates).
// Phase 1 (MFMA bf16 hi/lo) only selects candidates; tokens with a single
// in-band candidate and no in-band rival take it WITHOUT rescoring.
// Exact ties inside a tile force tB==tA -> fullmask -> full 32-scan.
//
// Round-11 (this file): FUSION. Rounds 1-4 proved the pipeline is latency-
// dominated end-to-end (vq_exact 68us at VALU 9% / HBM 13% / occ 18%; no
// pipe saturated), with ~100 MB of token-side intermediates (zf frags, tAB)
// bounced through L3 across 4 dependent launches, plus a 16x-amplified zf
// re-read (~540 MB L3) inside vq_approx. This version fuses token staging +
// MFMA scoring + selection + epilogue into ONE kernel: 64 tokens/block,
// 2048 blocks, ~33 KB LDS. zf frags and the (bit-identical) tAB float2 live
// in LDS; only the tiny code-side precompute (e_sq, ef frags) stays in a
// 4-block pre-kernel. Selection logic is round-4 verbatim; all frozen
// numerics (staging split, zsq, RESCORE, lex argmin) are byte-identical.
// Deliberate trade: ef A-frags re-read per block (~512 MB L2-resident,
// throughput, overlapped) in exchange for deleting all global token
// intermediates and two launches (latency).
// ---------------------------------------------------------------------------

static __device__ __forceinline__ unsigned short f2bf(float x) {  // RNE
    unsigned u = __float_as_uint(x);
    u += 0x7fffu + ((u >> 16) & 1u);
    return (unsigned short)(u >> 16);
}
static __device__ __forceinline__ float bf2f(unsigned short h) {
    return __uint_as_float(((unsigned)h) << 16);
}

// ---------------------------------------------------------------------------
// code pre: 4 blocks x 256 = 1024 codes. e_sq (frozen pairwise) + e bf16
// hi/lo fragments + zero counts shards / sse partials. Unchanged numerics.
// frag[(tile*8 + g)*32 + (code&31)], g = d/8.
// ---------------------------------------------------------------------------
__global__ __launch_bounds__(256) void vq_codes(const float* __restrict__ cb,
                                                float* __restrict__ e_sq,
                                                short8* __restrict__ efH,
                                                short8* __restrict__ efL,
                                                unsigned int* __restrict__ counts,
                                                float* __restrict__ sse_part)
{
#pragma clang fp contract(off)
    const int k = blockIdx.x * 256 + threadIdx.x;   // 0..1023
    const float4* ep = (const float4*)(cb + (size_t)k * ED);
    const int m = k & 31, ct = k >> 5;
    float r[8];
#pragma unroll
    for (int g = 0; g < 8; ++g) {
        float4 a = ep[2 * g], b = ep[2 * g + 1];
        float v[8] = {a.x, a.y, a.z, a.w, b.x, b.y, b.z, b.w};
        short8 hv, lv;
#pragma unroll
        for (int j = 0; j < 8; ++j) {
            unsigned short hb = f2bf(v[j]);
            hv[j] = (short)hb;
            lv[j] = (short)f2bf(v[j] - bf2f(hb));
            const float sq = v[j] * v[j];          // frozen pairwise e_sq
            r[j] = g ? (r[j] + sq) : sq;
        }
        efH[(ct * 8 + g) * 32 + m] = hv;
        efL[(ct * 8 + g) * 32 + m] = lv;
    }
    e_sq[k] = ((r[0] + r[1]) + (r[2] + r[3])) + ((r[4] + r[5]) + (r[6] + r[7]));
    counts[k]        = 0u;   // 4 shards
    counts[k + 1024] = 0u;
    counts[k + 2048] = 0u;
    counts[k + 3072] = 0u;
    if (k < 64) sse_part[k] = 0.f;
}

// ---------------------------------------------------------------------------
// Frozen exact rescore of code (cc): single sequential fmaf chain d=0..63,
// d2 = fmaf(-2,dot,zsq) + e_sq; lexicographic (d2, idx) update.
#define RESCORE(cc)                                                          \
    do {                                                                     \
        const int c_ = (cc);                                                 \
        const float4* e4_ = (const float4*)(cb + (size_t)c_ * ED);           \
        float a_ = 0.f;                                                      \
        _Pragma("unroll")                                                    \
        for (int jj_ = 0; jj_ < 16; ++jj_) {                                 \
            const float4 v_ = e4_[jj_];                                      \
            a_ = fmaf(zr[4 * jj_ + 0], v_.x, a_);                            \
            a_ = fmaf(zr[4 * jj_ + 1], v_.y, a_);                            \
            a_ = fmaf(zr[4 * jj_ + 2], v_.z, a_);                            \
            a_ = fmaf(zr[4 * jj_ + 3], v_.w, a_);                            \
        }                                                                    \
        const float d2_ = fmaf(-2.f, a_, zsq) + e_sq[c_];                    \
        if (d2_ < best || (d2_ == best && c_ < bi)) { best = d2_; bi = c_; } \
    } while (0)

// ---------------------------------------------------------------------------
// fused main: 64 tokens/block, 2048 blocks, 4 waves.
//  S: wave 0 stages z frags (H/L) + frozen zsq into LDS.
//  M: each wave owns tiles {g*8+wv*2, +1} per group g (4 groups); 24 MFMA
//     per token-tile; bit-identical (masked max, rival) float2 -> LDS sel.
//  R: waves 0-1, 2 lanes/token: round-4 selection verbatim from LDS.
//  E: all waves: coalesced epilogue (z_q gather/store, SSE), atomics.
// ---------------------------------------------------------------------------
__global__ __launch_bounds__(256, 3) void vq_main(const float* __restrict__ z_e,
                                                  const float* __restrict__ cb,
                                                  const float* __restrict__ e_sq,
                                                  const short8* __restrict__ efH,
                                                  const short8* __restrict__ efL,
                                                  float* __restrict__ out_zq,
                                                  float* __restrict__ out_idx,
                                                  unsigned int* __restrict__ counts,
                                                  float* __restrict__ sse_part)
{
#pragma clang fp contract(off)
    __shared__ short8 s_zfh[512];        // [2 tt][8 g][32 n]   8 KB
    __shared__ short8 s_zfl[512];        //                     8 KB
    __shared__ float2 s_sel[32 * 64];    // [tile][token]      16 KB
    __shared__ float  s_zsq[64];
    __shared__ int    s_bi[64];
    __shared__ float  s_wsse[4];

    const int tid = threadIdx.x;
    const int wv = tid >> 6, lane = tid & 63;
    const int h = lane >> 5, ml = lane & 31;
    const int t0 = blockIdx.x * 64;

    // ---- S: stage 64 token rows (frozen split + frozen pairwise zsq) -----
    if (tid < 64) {
        const float4* zp = (const float4*)(z_e + (size_t)(t0 + tid) * ED);
        const int n = tid & 31, ttl = tid >> 5;
        float r[8];
#pragma unroll
        for (int g = 0; g < 8; ++g) {
            float4 a = zp[2 * g], b = zp[2 * g + 1];
            float v[8] = {a.x, a.y, a.z, a.w, b.x, b.y, b.z, b.w};
            short8 hv, lv;
#pragma unroll
            for (int j = 0; j < 8; ++j) {
                unsigned short hb = f2bf(v[j]);
                hv[j] = (short)hb;
                lv[j] = (short)f2bf(v[j] - bf2f(hb));
                const float sq = v[j] * v[j];      // frozen pairwise zsq
                r[j] = g ? (r[j] + sq) : sq;
            }
            s_zfh[(ttl * 8 + g) * 32 + n] = hv;
            s_zfl[(ttl * 8 + g) * 32 + n] = lv;
        }
        s_zsq[tid] = ((r[0] + r[1]) + (r[2] + r[3])) + ((r[4] + r[5]) + (r[6] + r[7]));
    }
    __syncthreads();

    // ---- M: score all 32 code tiles (4 groups x 2 tiles/wave) ------------
    for (int g = 0; g < 4; ++g) {
        short8 ea[2][4], eb[2][4];                 // A-frags for this group
#pragma unroll
        for (int mt = 0; mt < 2; ++mt) {
            const int ct = g * 8 + wv * 2 + mt;
#pragma unroll
            for (int q = 0; q < 4; ++q) {
                const int idx = (ct * 8 + q * 2 + h) * 32 + ml;
                ea[mt][q] = efH[idx];
                eb[mt][q] = efL[idx];
            }
        }
#pragma unroll
        for (int it = 0; it < 2; ++it) {
            float16 acc0 = {}, acc1 = {};
#pragma unroll
            for (int q = 0; q < 4; ++q) {
                const int idx = (it * 8 + q * 2 + h) * 32 + ml;
                const short8 zh = s_zfh[idx];
                const short8 zl = s_zfl[idx];
                acc0 = __builtin_amdgcn_mfma_f32_32x32x16_bf16(ea[0][q], zh, acc0, 0, 0, 0);
                acc1 = __builtin_amdgcn_mfma_f32_32x32x16_bf16(ea[1][q], zh, acc1, 0, 0, 0);
                acc0 = __builtin_amdgcn_mfma_f32_32x32x16_bf16(ea[0][q], zl, acc0, 0, 0, 0);
                acc1 = __builtin_amdgcn_mfma_f32_32x32x16_bf16(ea[1][q], zl, acc1, 0, 0, 0);
                acc0 = __builtin_amdgcn_mfma_f32_32x32x16_bf16(eb[0][q], zh, acc0, 0, 0, 0);
                acc1 = __builtin_amdgcn_mfma_f32_32x32x16_bf16(eb[1][q], zh, acc1, 0, 0, 0);
            }
#pragma unroll
            for (int mt = 0; mt < 2; ++mt) {
                const float16 acc = mt ? acc1 : acc0;
                float v1 = -FLT_MAX, v2 = -FLT_MAX;
                int i1 = 0;
#pragma unroll
                for (int rg = 0; rg < 16; ++rg) {
                    const float v = acc[rg];
                    const int mrow = (rg & 3) + 8 * (rg >> 2) + 4 * h;  // C/D row
                    if (v > v1) { v2 = v1; v1 = v; i1 = mrow; }
                    else v2 = fmaxf(v2, v);
                }
                const float o1 = __shfl_xor(v1, 32);
                const float o2 = __shfl_xor(v2, 32);
                const int   oi = __shfl_xor(i1, 32);
                const float lo = fminf(v1, o1);
                if (o1 > v1) { v1 = o1; i1 = oi; }
                v2 = fmaxf(lo, fmaxf(v2, o2));      // exact 2nd-largest merge
                if (lane < 32) {
                    const unsigned bits = (__float_as_uint(-2.f * v1) & ~31u) | (unsigned)i1;
                    float2 o;
                    o.x = __uint_as_float(bits);    // bit-identical to old tA
                    o.y = -2.f * v2;                // bit-identical to old tB
                    s_sel[(g * 8 + wv * 2 + mt) * 64 + it * 32 + lane] = o;
                }
            }
        }
    }
    __syncthreads();

    // ---- R: selection (waves 0-1; 2 lanes/token; round-4 verbatim) -------
    if (wv < 2) {
        const int tls = (wv & 1) * 32 + ml;        // token slot 0..63
        const int t = t0 + tls;
        float av[16], bv[16];
        float m = FLT_MAX;
#pragma unroll
        for (int i = 0; i < 16; ++i) {
            const float2 p = s_sel[(h * 16 + i) * 64 + tls];
            av[i] = p.x; bv[i] = p.y;
            m = fminf(m, av[i]);
        }
        m = fminf(m, __shfl_xor(m, 32));           // pair min == frozen min32
        const float thr = m + EPS;

        unsigned band16 = 0u, full16 = 0u;
        int cand0 = 0, nb = 0;
#pragma unroll
        for (int i = 0; i < 16; ++i) {
            if (av[i] <= thr) {
                if (nb == 0)
                    cand0 = (h * 16 + i) * 32 + (int)(__float_as_uint(av[i]) & 31u);
                ++nb;
                band16 |= (1u << i);
                if (bv[i] <= thr) full16 |= (1u << i);
            }
        }
        const int nb_o = __shfl_xor(nb, 32);
        const int c0_o = __shfl_xor(cand0, 32);
        const unsigned full_o = (unsigned)__shfl_xor((int)full16, 32);

        int bsel;
        if ((nb + nb_o) == 1 && (full16 | full_o) == 0u) {
            bsel = h == 0 ? (nb ? cand0 : c0_o) : (nb_o ? c0_o : cand0);
        } else {
            // Rare path: frozen rescore; halves lex-merged (== seq 0..31 fold)
            const float4* zp = (const float4*)(z_e + (size_t)t * ED);
            float zr[ED];
#pragma unroll
            for (int i = 0; i < 16; ++i) {
                const float4 v = zp[i];
                zr[4 * i + 0] = v.x; zr[4 * i + 1] = v.y;
                zr[4 * i + 2] = v.z; zr[4 * i + 3] = v.w;
            }
            const float zsq = s_zsq[tls];
            float best = FLT_MAX;
            int bi = 0;
            unsigned rem = band16;
            while (rem) {
                const int i = __ffs(rem) - 1;
                rem &= rem - 1;
                const int ct = h * 16 + i;
                if (full16 & (1u << i)) {
                    for (int j = 0; j < 32; ++j) RESCORE(ct * 32 + j);
                } else {
                    RESCORE(ct * 32 + (int)(__float_as_uint(av[i]) & 31u));
                }
            }
            const float ob  = __shfl_xor(best, 32);
            const int   obi = __shfl_xor(bi, 32);
            if (ob < best || (ob == best && obi < bi)) { best = ob; bi = obi; }
            bsel = bi;
        }

        if (h == 0) {
            s_bi[tls] = bsel;
            out_idx[t] = (float)bsel;
            atomicAdd(&counts[(blockIdx.x & 3) * K_CODES + bsel], 1u);  // sharded
        }
    }
    __syncthreads();

    // ---- E: epilogue, flat-contiguous (thread <-> float4) ----------------
    const float4* z4  = (const float4*)z_e + (size_t)t0 * 16;
    float4*       o4  = (float4*)out_zq + (size_t)t0 * 16;
    const float4* eq4 = (const float4*)cb;
    float lsse = 0.f;
#pragma unroll
    for (int p = 0; p < 4; ++p) {
        const int f = p * 256 + tid;               // 0..1023 float4s
        const int bq = s_bi[f >> 4];
        const float4 q  = eq4[(size_t)bq * 16 + (f & 15)];
        const float4 zv = z4[f];
        o4[f] = q;
        float dx = q.x - zv.x; lsse = fmaf(dx, dx, lsse);
        float dy = q.y - zv.y; lsse = fmaf(dy, dy, lsse);
        float dz = q.z - zv.z; lsse = fmaf(dz, dz, lsse);
        float dw = q.w - zv.w; lsse = fmaf(dw, dw, lsse);
    }
#pragma unroll
    for (int off = 32; off > 0; off >>= 1)
        lsse += __shfl_down(lsse, off, 64);
    if (lane == 0) s_wsse[wv] = lsse;
    __syncthreads();
    if (tid == 0)
        atomicAdd(&sse_part[blockIdx.x & 63],
                  (s_wsse[0] + s_wsse[1]) + (s_wsse[2] + s_wsse[3]));
}

// ---------------------------------------------------------------------------
// final: entropy / losses scalars (sums 4 count shards + 64 SSE partials)
// ---------------------------------------------------------------------------
__global__ __launch_bounds__(1024) void vq_final(const unsigned int* __restrict__ counts,
                                                 const float* __restrict__ sse_part,
                                                 float* __restrict__ out_sc)
{
    __shared__ float red[1024];
    const int i = threadIdx.x;
    const unsigned int cu = counts[i] + counts[i + 1024]
                          + counts[i + 2048] + counts[i + 3072];
    const float c = (float)cu;
    const float p = c / (float)NTOK + 1e-10f;
    red[i] = p * logf(p);
    __syncthreads();
    for (int s = 512; s > 0; s >>= 1) {
        if (i < s) red[i] += red[i + s];
        __syncthreads();
    }
    if (i == 0) {
        const float entropy = -red[0];
        float ssum = 0.f;
        for (int k = 0; k < 64; ++k) ssum += sse_part[k];
        const float cbl = ssum / ((float)NTOK * (float)ED);
        out_sc[0] = cbl;                                   // codebook_loss
        out_sc[1] = 0.25f * cbl;                           // commitment_loss
        out_sc[2] = -0.1f * (entropy / 6.93147180559945f); // entropy_loss
        out_sc[3] = expf(entropy);                         // perplexity
    }
}

// ---------------------------------------------------------------------------
extern "C" void kernel_launch(void* const* d_in, const int* in_sizes, int n_in,
                              void* d_out, int out_size, void* d_ws, size_t ws_size,
                              hipStream_t stream)
{
    const float* z_e = (const float*)d_in[0];
    const float* cb  = (const float*)d_in[1];

    float* out   = (float*)d_out;
    float* o_zq  = out;                              // [131072,64]
    float* o_idx = out + (size_t)NTOK * ED;          // [131072] (as float)
    float* o_sc  = o_idx + NTOK;                     // 4 scalars

    char* ws = (char*)d_ws;
    float*        e_sq     = (float*)(ws);                   // 4 KB
    unsigned int* counts   = (unsigned int*)(ws + 4096);     // 16 KB (4 shards)
    float*        sse_part = (float*)(ws + 20480);           // 256 B
    short8*       efH      = (short8*)(ws + 32768);          // 128 KB
    short8*       efL      = (short8*)(ws + 163840);         // 128 KB (ends 288 KB)

    vq_codes<<<4, 256, 0, stream>>>(cb, e_sq, efH, efL, counts, sse_part);
    vq_main <<<NTOK / 64, 256, 0, stream>>>(z_e, cb, e_sq, efH, efL,
                                            o_zq, o_idx, counts, sse_part);
    vq_final<<<1, 1024, 0, stream>>>(counts, sse_part, o_sc);
}